// Round 11
// baseline (418.925 us; speedup 1.0000x reference)
//
#include <hip/hip_runtime.h>
#include <math.h>

#define N_NODES  100000
#define N_EDGES  1600000
#define NF       64
#define N_GRAPHS 256

#define BSH   7                                   // 128 nodes per bucket
#define NB    ((N_NODES + 127) / 128)             // 782 buckets
#define BCAP  2600                                // per-bucket scratch capacity
#define NBLKS ((N_NODES + 63) / 64)               // 1563 node-tile blocks

typedef float f32x2 __attribute__((ext_vector_type(2)));

// ---------------- zero bucket allocator + pool sums ------------------------
__global__ void k_zeroinit(int* __restrict__ bucketCur, float* __restrict__ gsums) {
    int i = blockIdx.x * blockDim.x + threadIdx.x;
    if (i < NB) bucketCur[i] = 0;
    if (i < N_GRAPHS * NF) gsums[i] = 0.0f;
}

// ---------------- bucket scatter: LDS-aggregated, 1 atomic/(block,bucket) --
__global__ __launch_bounds__(1024) void k_bscatter(const int* __restrict__ src,
                                                   const int* __restrict__ dst,
                                                   int* __restrict__ bucketCur,
                                                   int* __restrict__ scratch) {
    __shared__ int hist[NB];
    __shared__ int bbase[NB];
    int t = threadIdx.x;
    for (int i = t; i < NB; i += 1024) hist[i] = 0;
    __syncthreads();
    int e0 = (blockIdx.x * 1024 + t) * 8;
    int d[8], s[8], r[8];
    bool act = (e0 + 7) < N_EDGES;          // E % 8 == 0
    if (act) {
        *(int4*)&d[0] = *(const int4*)(dst + e0);
        *(int4*)&d[4] = *(const int4*)(dst + e0 + 4);
        *(int4*)&s[0] = *(const int4*)(src + e0);
        *(int4*)&s[4] = *(const int4*)(src + e0 + 4);
#pragma unroll
        for (int k = 0; k < 8; ++k) r[k] = atomicAdd(&hist[d[k] >> BSH], 1);
    }
    __syncthreads();
    for (int i = t; i < NB; i += 1024)
        if (hist[i]) bbase[i] = atomicAdd(&bucketCur[i], hist[i]);
    __syncthreads();
    if (act) {
#pragma unroll
        for (int k = 0; k < 8; ++k) {
            int b = d[k] >> BSH;
            int pos = bbase[b] + r[k];
            if (pos < BCAP)
                scratch[b * BCAP + pos] = ((d[k] & 127) << 17) | s[k];
        }
    }
}

// ---------------- scan bucket counts -> bucketPtr --------------------------
__global__ __launch_bounds__(1024) void k_bscan(const int* __restrict__ bucketCur,
                                                int* __restrict__ bucketPtr,
                                                int* __restrict__ rowptr) {
    int t = threadIdx.x;
    __shared__ int ps[1024];
    int v = (t < NB) ? min(bucketCur[t], BCAP) : 0;
    ps[t] = v;
    __syncthreads();
#pragma unroll
    for (int off = 1; off < 1024; off <<= 1) {
        int u = (t >= off) ? ps[t - off] : 0;
        __syncthreads();
        ps[t] += u;
        __syncthreads();
    }
    if (t < NB) bucketPtr[t] = ps[t] - v;        // exclusive
    if (t == NB - 1) {
        bucketPtr[NB] = ps[t];
        rowptr[N_NODES] = ps[t];                 // == N_EDGES
    }
}

// ---------------- per-bucket CSR finalize: rowptr, dinv, col ---------------
__global__ __launch_bounds__(256) void k_bfinal(const int* __restrict__ bucketCur,
                                                const int* __restrict__ bucketPtr,
                                                const int* __restrict__ scratch,
                                                int* __restrict__ rowptr,
                                                float* __restrict__ dinv,
                                                int* __restrict__ col) {
    int b = blockIdx.x;
    int cnt  = min(bucketCur[b], BCAP);
    int base = bucketPtr[b];
    int node0 = b << BSH;
    __shared__ int hist[128];
    __shared__ int escan[128];
    __shared__ int ps[128];
    __shared__ int rnk[BCAP];
    int t = threadIdx.x;
    if (t < 128) hist[t] = 0;
    __syncthreads();
    const int* sp = scratch + b * BCAP;
    for (int j = t; j < cnt; j += 256)
        rnk[j] = atomicAdd(&hist[sp[j] >> 17], 1);
    __syncthreads();
    int hv = (t < 128) ? hist[t] : 0;
    if (t < 128) ps[t] = hv;
    __syncthreads();
#pragma unroll
    for (int off = 1; off < 128; off <<= 1) {
        int u = 0;
        if (t < 128 && t >= off) u = ps[t - off];
        __syncthreads();
        if (t < 128) ps[t] += u;
        __syncthreads();
    }
    if (t < 128) {
        int excl = ps[t] - hv;
        escan[t] = excl;
        int node = node0 + t;
        if (node < N_NODES) {
            rowptr[node] = base + excl;
            dinv[node] = rsqrtf((float)(hv + 1));   // self-loop adds 1
        }
    }
    __syncthreads();
    for (int j = t; j < cnt; j += 256) {
        int pk = sp[j];
        col[base + escan[pk >> 17] + rnk[j]] = pk & 0x1FFFF;
    }
}

// ---------------- layer-1 GEMM: A1 = fp8(dinv * (X @ W1)), split halves ----
__global__ __launch_bounds__(256) void k_gemm1(const float* __restrict__ X,
                                               const float* __restrict__ W,
                                               const float* __restrict__ dinv,
                                               int* __restrict__ A1a,
                                               int* __restrict__ A1b) {
    __shared__ float Ws[64][64];       // [k][col]
    __shared__ float Xs[64][68];       // [k][node]
    int t  = threadIdx.x;
    int n0 = blockIdx.x * 64;

    for (int i = t; i < 64 * 64; i += 256) Ws[i >> 6][i & 63] = W[i];

#pragma unroll
    for (int p = 0; p < 4; ++p) {
        int flat = p * 256 + t;                  // 0..1023
        int nl = flat >> 4;
        int kg = flat & 15;
        int node = n0 + nl;
        float4 v = make_float4(0.f, 0.f, 0.f, 0.f);
        if (node < N_NODES) v = *(const float4*)(X + (size_t)node * NF + kg * 4);
        Xs[kg * 4 + 0][nl] = v.x;
        Xs[kg * 4 + 1][nl] = v.y;
        Xs[kg * 4 + 2][nl] = v.z;
        Xs[kg * 4 + 3][nl] = v.w;
    }
    __syncthreads();

    int tx = t & 15;
    int ty = t >> 4;
    float acc[4][4];
#pragma unroll
    for (int i = 0; i < 4; ++i)
#pragma unroll
        for (int j = 0; j < 4; ++j) acc[i][j] = 0.f;

#pragma unroll 8
    for (int k = 0; k < 64; ++k) {
        float4 wv = *(const float4*)&Ws[k][tx * 4];
        float4 xv = *(const float4*)&Xs[k][ty * 4];
        acc[0][0] += xv.x * wv.x; acc[0][1] += xv.x * wv.y;
        acc[0][2] += xv.x * wv.z; acc[0][3] += xv.x * wv.w;
        acc[1][0] += xv.y * wv.x; acc[1][1] += xv.y * wv.y;
        acc[1][2] += xv.y * wv.z; acc[1][3] += xv.y * wv.w;
        acc[2][0] += xv.z * wv.x; acc[2][1] += xv.z * wv.y;
        acc[2][2] += xv.z * wv.z; acc[2][3] += xv.z * wv.w;
        acc[3][0] += xv.w * wv.x; acc[3][1] += xv.w * wv.y;
        acc[3][2] += xv.w * wv.z; acc[3][3] += xv.w * wv.w;
    }

#pragma unroll
    for (int i = 0; i < 4; ++i) {
        int node = n0 + ty * 4 + i;
        if (node < N_NODES) {
            float dv = dinv[node];
            int pk = 0;
            pk = __builtin_amdgcn_cvt_pk_fp8_f32(acc[i][0] * dv, acc[i][1] * dv, pk, false);
            pk = __builtin_amdgcn_cvt_pk_fp8_f32(acc[i][2] * dv, acc[i][3] * dv, pk, true);
            if (tx < 8) __builtin_nontemporal_store(pk, &A1a[(size_t)node * 8 + tx]);
            else        __builtin_nontemporal_store(pk, &A1b[(size_t)node * 8 + tx - 8]);
        }
    }
}

// ---------------- pull one 32B half-row for one node (4 lanes/edge) --------
// slot = lane>>2 (16 edge slots), quad = lane&3 (8 features each).
__device__ __forceinline__ void pull_half(const int* __restrict__ A,
                                          const int* __restrict__ col,
                                          int n, int beg, int cnt,
                                          int slot, int quad, float acc[8]) {
#pragma unroll
    for (int k = 0; k < 8; ++k) acc[k] = 0.f;
    for (int base = slot; base < cnt; base += 64) {
        int cidx[4];
#pragma unroll
        for (int p = 0; p < 4; ++p) {
            int idx = base + p * 16;
            cidx[p] = (idx < cnt) ? ((idx == 0) ? n : col[beg + idx - 1]) : -1;
        }
#pragma unroll
        for (int p = 0; p < 4; ++p) {
            int s = cidx[p];
            if (s >= 0) {
                int2 raw = *(const int2*)(A + (size_t)s * 8 + quad * 2);
                f32x2 f0 = __builtin_amdgcn_cvt_pk_f32_fp8(raw.x, false);
                f32x2 f1 = __builtin_amdgcn_cvt_pk_f32_fp8(raw.x, true);
                f32x2 f2 = __builtin_amdgcn_cvt_pk_f32_fp8(raw.y, false);
                f32x2 f3 = __builtin_amdgcn_cvt_pk_f32_fp8(raw.y, true);
                acc[0] += f0.x; acc[1] += f0.y; acc[2] += f1.x; acc[3] += f1.y;
                acc[4] += f2.x; acc[5] += f2.y; acc[6] += f3.x; acc[7] += f3.y;
            }
        }
    }
#pragma unroll
    for (int off = 4; off < 64; off <<= 1)
#pragma unroll
        for (int k = 0; k < 8; ++k) acc[k] += __shfl_down(acc[k], off);
}

// ---------------- fused: pull1 + b1 + relu -> GEMM(W2) -> fp8 A2 -----------
__global__ __launch_bounds__(256) void k_layer2(const int* __restrict__ rowptr,
                                                const int* __restrict__ col,
                                                const float* __restrict__ dinv,
                                                const int* __restrict__ A1a,
                                                const int* __restrict__ A1b,
                                                const float* __restrict__ b1,
                                                const float* __restrict__ W2,
                                                int* __restrict__ A2a,
                                                int* __restrict__ A2b) {
    __shared__ float Ws[64][64];
    __shared__ float Xs[64][68];
    int t = threadIdx.x;
    int n0 = blockIdx.x * 64;
    for (int i = t; i < 64 * 64; i += 256) Ws[i >> 6][i & 63] = W2[i];
    int wid = t >> 6, lane = t & 63, slot = lane >> 2, quad = lane & 3;

    for (int h = 0; h < 2; ++h) {
        const int* A = h ? A1b : A1a;
        for (int i = 0; i < 16; ++i) {
            int nl = wid * 16 + i;
            int n = n0 + nl;
            int fb = h * 32 + quad * 8;
            if (n < N_NODES) {
                int beg = rowptr[n];
                int cnt = rowptr[n + 1] - beg + 1;
                float acc[8];
                pull_half(A, col, n, beg, cnt, slot, quad, acc);
                if (slot == 0) {
                    float dv = dinv[n];
#pragma unroll
                    for (int k = 0; k < 8; ++k) {
                        float v = acc[k] * dv + b1[fb + k];
                        Xs[fb + k][nl] = v > 0.f ? v : 0.f;
                    }
                }
            } else if (slot == 0) {
#pragma unroll
                for (int k = 0; k < 8; ++k) Xs[fb + k][nl] = 0.f;
            }
        }
    }
    __syncthreads();

    int tx = t & 15, ty = t >> 4;
    float acc[4][4];
#pragma unroll
    for (int i = 0; i < 4; ++i)
#pragma unroll
        for (int j = 0; j < 4; ++j) acc[i][j] = 0.f;

#pragma unroll 8
    for (int k = 0; k < 64; ++k) {
        float4 wv = *(const float4*)&Ws[k][tx * 4];
        float4 xv = *(const float4*)&Xs[k][ty * 4];
        acc[0][0] += xv.x * wv.x; acc[0][1] += xv.x * wv.y;
        acc[0][2] += xv.x * wv.z; acc[0][3] += xv.x * wv.w;
        acc[1][0] += xv.y * wv.x; acc[1][1] += xv.y * wv.y;
        acc[1][2] += xv.y * wv.z; acc[1][3] += xv.y * wv.w;
        acc[2][0] += xv.z * wv.x; acc[2][1] += xv.z * wv.y;
        acc[2][2] += xv.z * wv.z; acc[2][3] += xv.z * wv.w;
        acc[3][0] += xv.w * wv.x; acc[3][1] += xv.w * wv.y;
        acc[3][2] += xv.w * wv.z; acc[3][3] += xv.w * wv.w;
    }

#pragma unroll
    for (int i = 0; i < 4; ++i) {
        int node = n0 + ty * 4 + i;
        if (node < N_NODES) {
            float dv = dinv[node];
            int pk = 0;
            pk = __builtin_amdgcn_cvt_pk_fp8_f32(acc[i][0] * dv, acc[i][1] * dv, pk, false);
            pk = __builtin_amdgcn_cvt_pk_fp8_f32(acc[i][2] * dv, acc[i][3] * dv, pk, true);
            if (tx < 8) __builtin_nontemporal_store(pk, &A2a[(size_t)node * 8 + tx]);
            else        __builtin_nontemporal_store(pk, &A2b[(size_t)node * 8 + tx - 8]);
        }
    }
}

// ---------------- fused: pull2 + b2 + relu + mean-pool partials ------------
__global__ __launch_bounds__(256) void k_pool2(const int* __restrict__ rowptr,
                                               const int* __restrict__ col,
                                               const float* __restrict__ dinv,
                                               const int* __restrict__ A2a,
                                               const int* __restrict__ A2b,
                                               const float* __restrict__ b2,
                                               const int* __restrict__ batch,
                                               float* __restrict__ gsums) {
    __shared__ float gs[8][64];
    __shared__ int sgmin;
    int t = threadIdx.x;
    int n0 = blockIdx.x * 64;
    if (t == 0) sgmin = batch[n0];
    for (int i = t; i < 8 * 64; i += 256) gs[i >> 6][i & 63] = 0.f;
    __syncthreads();
    int gmin = sgmin;
    int wid = t >> 6, lane = t & 63, slot = lane >> 2, quad = lane & 3;

    for (int h = 0; h < 2; ++h) {
        const int* A = h ? A2b : A2a;
        for (int i = 0; i < 16; ++i) {
            int nl = wid * 16 + i;
            int n = n0 + nl;
            if (n >= N_NODES) continue;           // uniform per wave
            int beg = rowptr[n];
            int cnt = rowptr[n + 1] - beg + 1;
            float acc[8];
            pull_half(A, col, n, beg, cnt, slot, quad, acc);
            if (slot == 0) {
                float dv = dinv[n];
                int g = batch[n];
                int li = g - gmin;
                int fb = h * 32 + quad * 8;
#pragma unroll
                for (int k = 0; k < 8; ++k) {
                    float v = acc[k] * dv + b2[fb + k];
                    v = v > 0.f ? v : 0.f;
                    if (li < 8) atomicAdd(&gs[li][fb + k], v);
                    else        atomicAdd(&gsums[g * NF + fb + k], v);
                }
            }
        }
    }
    __syncthreads();
    for (int j = t; j < 8 * 64; j += 256) {
        float v = gs[j >> 6][j & 63];
        if (v != 0.f) atomicAdd(&gsums[(gmin + (j >> 6)) * NF + (j & 63)], v);
    }
}

// ---------------- head: mean + fc + sigmoid, one wave per graph ------------
__device__ __forceinline__ int lower_bound_i(const int* __restrict__ a, int n, int key) {
    int lo = 0, hi = n;
    while (lo < hi) {
        int mid = (lo + hi) >> 1;
        if (a[mid] < key) lo = mid + 1; else hi = mid;
    }
    return lo;
}

__global__ __launch_bounds__(256) void k_head(const float* __restrict__ gsums,
                                              const int* __restrict__ batch,
                                              const float* __restrict__ Wfc,
                                              const float* __restrict__ bfc,
                                              float* __restrict__ out) {
    int g    = (blockIdx.x * blockDim.x + threadIdx.x) >> 6;
    int lane = threadIdx.x & 63;
    if (g >= N_GRAPHS) return;
    int lo = lower_bound_i(batch, N_NODES, g);
    int hi = lower_bound_i(batch, N_NODES, g + 1);
    int cnt = hi - lo;
    float c = cnt > 0 ? (float)cnt : 1.0f;
    float v = (gsums[g * NF + lane] / c) * Wfc[lane];
#pragma unroll
    for (int off = 32; off > 0; off >>= 1) v += __shfl_down(v, off);
    if (lane == 0) out[g] = 1.0f / (1.0f + expf(-(v + bfc[0])));
}

extern "C" void kernel_launch(void* const* d_in, const int* in_sizes, int n_in,
                              void* d_out, int out_size, void* d_ws, size_t ws_size,
                              hipStream_t stream) {
    const float* x    = (const float*)d_in[0];
    const int*   ei   = (const int*)d_in[1];
    const int*   batch= (const int*)d_in[2];
    const float* W1   = (const float*)d_in[3];
    const float* b1   = (const float*)d_in[4];
    const float* W2   = (const float*)d_in[5];
    const float* b2   = (const float*)d_in[6];
    const float* Wfc  = (const float*)d_in[7];
    const float* bfc  = (const float*)d_in[8];
    float* out = (float*)d_out;

    const int* src = ei;
    const int* dst = ei + N_EDGES;

    // workspace layout (fp8 half-arrays first, 16B aligned)
    int*   A1a       = (int*)d_ws;                       // N*8 ints (32B half-rows)
    int*   A1b       = A1a + (size_t)N_NODES * 8;        // N*8
    int*   A2a       = A1b + (size_t)N_NODES * 8;        // N*8
    int*   A2b       = A2a + (size_t)N_NODES * 8;        // N*8
    float* dinv      = (float*)(A2b + (size_t)N_NODES * 8); // N
    int*   rowptr    = (int*)(dinv + N_NODES);           // N+1
    int*   bucketCur = rowptr + N_NODES + 1;             // NB
    int*   bucketPtr = bucketCur + NB;                   // NB+1
    float* gsums     = (float*)(bucketPtr + NB + 1);     // G*64
    int*   col       = (int*)(gsums + N_GRAPHS * NF);    // E
    int*   scratch   = col + N_EDGES;                    // NB*BCAP

    int g_bsc = (N_EDGES / 8 + 1023) / 1024;             // 196

    // ---- init + CSR build (counting sort by 128-node buckets) ----
    k_zeroinit<<<64, 256, 0, stream>>>(bucketCur, gsums);
    k_bscatter<<<g_bsc, 1024, 0, stream>>>(src, dst, bucketCur, scratch);
    k_bscan<<<1, 1024, 0, stream>>>(bucketCur, bucketPtr, rowptr);
    k_bfinal<<<NB, 256, 0, stream>>>(bucketCur, bucketPtr, scratch, rowptr, dinv, col);

    // ---- layer 1 GEMM:  A1 = fp8(dinv * (x @ W1)) ----
    k_gemm1<<<NBLKS, 256, 0, stream>>>(x, W1, dinv, A1a, A1b);

    // ---- fused layer 2: pull(A1) + b1 + relu -> @W2 -> fp8 A2 ----
    k_layer2<<<NBLKS, 256, 0, stream>>>(rowptr, col, dinv, A1a, A1b, b1, W2, A2a, A2b);

    // ---- fused pool: pull(A2) + b2 + relu -> per-graph sums ----
    k_pool2<<<NBLKS, 256, 0, stream>>>(rowptr, col, dinv, A2a, A2b, b2, batch, gsums);

    // ---- head: mean + fc + sigmoid ----
    k_head<<<64, 256, 0, stream>>>(gsums, batch, Wfc, bfc, out);
}

// Round 12
// 312.309 us; speedup vs baseline: 1.3414x; 1.3414x over previous
//
#include <hip/hip_runtime.h>
#include <math.h>

#define N_NODES  100000
#define N_EDGES  1600000
#define NF       64
#define N_GRAPHS 256

#define BSH   7                                   // 128 nodes per bucket
#define NB    ((N_NODES + 127) / 128)             // 782 buckets
#define BCAP  2600                                // per-bucket scratch capacity
#define NBLKS ((N_NODES + 63) / 64)               // 1563 node-tile blocks

typedef float f32x2 __attribute__((ext_vector_type(2)));

// ---------------- zero bucket allocator ------------------------------------
__global__ void k_zerocur(int* __restrict__ bucketCur) {
    int i = blockIdx.x * blockDim.x + threadIdx.x;
    if (i < NB) bucketCur[i] = 0;
}

// ---------------- bucket scatter: LDS-aggregated, 1 atomic/(block,bucket) --
__global__ __launch_bounds__(1024) void k_bscatter(const int* __restrict__ src,
                                                   const int* __restrict__ dst,
                                                   int* __restrict__ bucketCur,
                                                   int* __restrict__ scratch) {
    __shared__ int hist[NB];
    __shared__ int bbase[NB];
    int t = threadIdx.x;
    for (int i = t; i < NB; i += 1024) hist[i] = 0;
    __syncthreads();
    int e0 = (blockIdx.x * 1024 + t) * 8;
    int d[8], s[8], r[8];
    bool act = (e0 + 7) < N_EDGES;          // E % 8 == 0
    if (act) {
        *(int4*)&d[0] = *(const int4*)(dst + e0);
        *(int4*)&d[4] = *(const int4*)(dst + e0 + 4);
        *(int4*)&s[0] = *(const int4*)(src + e0);
        *(int4*)&s[4] = *(const int4*)(src + e0 + 4);
#pragma unroll
        for (int k = 0; k < 8; ++k) r[k] = atomicAdd(&hist[d[k] >> BSH], 1);
    }
    __syncthreads();
    for (int i = t; i < NB; i += 1024)
        if (hist[i]) bbase[i] = atomicAdd(&bucketCur[i], hist[i]);
    __syncthreads();
    if (act) {
#pragma unroll
        for (int k = 0; k < 8; ++k) {
            int b = d[k] >> BSH;
            int pos = bbase[b] + r[k];
            if (pos < BCAP)
                scratch[b * BCAP + pos] = ((d[k] & 127) << 17) | s[k];
        }
    }
}

// ---------------- scan bucket counts -> bucketPtr --------------------------
__global__ __launch_bounds__(1024) void k_bscan(const int* __restrict__ bucketCur,
                                                int* __restrict__ bucketPtr,
                                                int* __restrict__ rowptr) {
    int t = threadIdx.x;
    __shared__ int ps[1024];
    int v = (t < NB) ? min(bucketCur[t], BCAP) : 0;
    ps[t] = v;
    __syncthreads();
#pragma unroll
    for (int off = 1; off < 1024; off <<= 1) {
        int u = (t >= off) ? ps[t - off] : 0;
        __syncthreads();
        ps[t] += u;
        __syncthreads();
    }
    if (t < NB) bucketPtr[t] = ps[t] - v;        // exclusive
    if (t == NB - 1) {
        bucketPtr[NB] = ps[t];
        rowptr[N_NODES] = ps[t];                 // == N_EDGES
    }
}

// ---------------- per-bucket CSR finalize: rowptr, dinv, col ---------------
__global__ __launch_bounds__(256) void k_bfinal(const int* __restrict__ bucketCur,
                                                const int* __restrict__ bucketPtr,
                                                const int* __restrict__ scratch,
                                                int* __restrict__ rowptr,
                                                float* __restrict__ dinv,
                                                int* __restrict__ col) {
    int b = blockIdx.x;
    int cnt  = min(bucketCur[b], BCAP);
    int base = bucketPtr[b];
    int node0 = b << BSH;
    __shared__ int hist[128];
    __shared__ int escan[128];
    __shared__ int ps[128];
    __shared__ int rnk[BCAP];
    int t = threadIdx.x;
    if (t < 128) hist[t] = 0;
    __syncthreads();
    const int* sp = scratch + b * BCAP;
    for (int j = t; j < cnt; j += 256)
        rnk[j] = atomicAdd(&hist[sp[j] >> 17], 1);
    __syncthreads();
    int hv = (t < 128) ? hist[t] : 0;
    if (t < 128) ps[t] = hv;
    __syncthreads();
#pragma unroll
    for (int off = 1; off < 128; off <<= 1) {
        int u = 0;
        if (t < 128 && t >= off) u = ps[t - off];
        __syncthreads();
        if (t < 128) ps[t] += u;
        __syncthreads();
    }
    if (t < 128) {
        int excl = ps[t] - hv;
        escan[t] = excl;
        int node = node0 + t;
        if (node < N_NODES) {
            rowptr[node] = base + excl;
            dinv[node] = rsqrtf((float)(hv + 1));   // self-loop adds 1
        }
    }
    __syncthreads();
    for (int j = t; j < cnt; j += 256) {
        int pk = sp[j];
        col[base + escan[pk >> 17] + rnk[j]] = pk & 0x1FFFF;
    }
}

// ---------------- A' = dinv * (act(X [+bias,relu]) @ W), fp8 split halves --
// Block tile: 64 nodes x 64 cols; thread tile 4x4. Half-row = 8 ints = 32 B.
__global__ __launch_bounds__(256) void k_gemm(const float* __restrict__ X,
                                              const float* __restrict__ W,
                                              const float* __restrict__ bias,
                                              const float* __restrict__ dinv,
                                              int* __restrict__ Aa,
                                              int* __restrict__ Ab) {
    __shared__ float Ws[64][64];       // [k][col]
    __shared__ float Xs[64][68];       // [k][node], padded
    int t  = threadIdx.x;
    int n0 = blockIdx.x * 64;

    for (int i = t; i < 64 * 64; i += 256) Ws[i >> 6][i & 63] = W[i];

#pragma unroll
    for (int p = 0; p < 4; ++p) {
        int flat = p * 256 + t;                  // 0..1023
        int nl = flat >> 4;                      // local node 0..63
        int kg = flat & 15;                      // k-group (4 floats)
        int node = n0 + nl;
        float4 v = make_float4(0.f, 0.f, 0.f, 0.f);
        if (node < N_NODES) {
            v = *(const float4*)(X + (size_t)node * NF + kg * 4);
            if (bias) {
                v.x += bias[kg * 4 + 0]; v.x = v.x > 0.f ? v.x : 0.f;
                v.y += bias[kg * 4 + 1]; v.y = v.y > 0.f ? v.y : 0.f;
                v.z += bias[kg * 4 + 2]; v.z = v.z > 0.f ? v.z : 0.f;
                v.w += bias[kg * 4 + 3]; v.w = v.w > 0.f ? v.w : 0.f;
            }
        }
        Xs[kg * 4 + 0][nl] = v.x;
        Xs[kg * 4 + 1][nl] = v.y;
        Xs[kg * 4 + 2][nl] = v.z;
        Xs[kg * 4 + 3][nl] = v.w;
    }
    __syncthreads();

    int tx = t & 15;          // col group: cols 4*tx..+3
    int ty = t >> 4;          // node group: nodes 4*ty..+3
    float acc[4][4];
#pragma unroll
    for (int i = 0; i < 4; ++i)
#pragma unroll
        for (int j = 0; j < 4; ++j) acc[i][j] = 0.f;

#pragma unroll 8
    for (int k = 0; k < 64; ++k) {
        float4 wv = *(const float4*)&Ws[k][tx * 4];
        float4 xv = *(const float4*)&Xs[k][ty * 4];
        acc[0][0] += xv.x * wv.x; acc[0][1] += xv.x * wv.y;
        acc[0][2] += xv.x * wv.z; acc[0][3] += xv.x * wv.w;
        acc[1][0] += xv.y * wv.x; acc[1][1] += xv.y * wv.y;
        acc[1][2] += xv.y * wv.z; acc[1][3] += xv.y * wv.w;
        acc[2][0] += xv.z * wv.x; acc[2][1] += xv.z * wv.y;
        acc[2][2] += xv.z * wv.z; acc[2][3] += xv.z * wv.w;
        acc[3][0] += xv.w * wv.x; acc[3][1] += xv.w * wv.y;
        acc[3][2] += xv.w * wv.z; acc[3][3] += xv.w * wv.w;
    }

#pragma unroll
    for (int i = 0; i < 4; ++i) {
        int node = n0 + ty * 4 + i;
        if (node < N_NODES) {
            float dv = dinv[node];
            int pk = 0;
            pk = __builtin_amdgcn_cvt_pk_fp8_f32(acc[i][0] * dv, acc[i][1] * dv, pk, false);
            pk = __builtin_amdgcn_cvt_pk_fp8_f32(acc[i][2] * dv, acc[i][3] * dv, pk, true);
            if (tx < 8) Aa[(size_t)node * 8 + tx] = pk;
            else        Ab[(size_t)node * 8 + tx - 8] = pk;
        }
    }
}

// ---------------- pull aggregation: two L2-resident phases -----------------
// Half-row = 32 B: quad = lane&3 picks 8B (8 features), slot = lane>>2 picks
// the edge (16 slots in flight). Phase h gathers from a 3.2 MB array.
__global__ __launch_bounds__(256) void k_pull(const int* __restrict__ rowptr,
                                              const int* __restrict__ col,
                                              const float* __restrict__ dinv,
                                              const int* __restrict__ Aa,
                                              const int* __restrict__ Ab,
                                              float* __restrict__ B) {
    int n    = (blockIdx.x * blockDim.x + threadIdx.x) >> 6;
    int lane = threadIdx.x & 63;
    if (n >= N_NODES) return;
    int slot = lane >> 2;
    int quad = lane & 3;
    int beg = rowptr[n];
    int cnt = rowptr[n + 1] - beg + 1;      // + self
    float dv = dinv[n];

#pragma unroll
    for (int h = 0; h < 2; ++h) {
        const int* __restrict__ A = h ? Ab : Aa;
        float acc[8];
#pragma unroll
        for (int k = 0; k < 8; ++k) acc[k] = 0.f;

        for (int base = slot; base < cnt; base += 64) {
            int cidx[4];
#pragma unroll
            for (int p = 0; p < 4; ++p) {
                int idx = base + p * 16;
                cidx[p] = (idx < cnt) ? ((idx == 0) ? n : col[beg + idx - 1]) : -1;
            }
#pragma unroll
            for (int p = 0; p < 4; ++p) {
                int s = cidx[p];
                if (s >= 0) {
                    int2 raw = *(const int2*)(A + (size_t)s * 8 + quad * 2);
                    f32x2 f0 = __builtin_amdgcn_cvt_pk_f32_fp8(raw.x, false);
                    f32x2 f1 = __builtin_amdgcn_cvt_pk_f32_fp8(raw.x, true);
                    f32x2 f2 = __builtin_amdgcn_cvt_pk_f32_fp8(raw.y, false);
                    f32x2 f3 = __builtin_amdgcn_cvt_pk_f32_fp8(raw.y, true);
                    acc[0] += f0.x; acc[1] += f0.y; acc[2] += f1.x; acc[3] += f1.y;
                    acc[4] += f2.x; acc[5] += f2.y; acc[6] += f3.x; acc[7] += f3.y;
                }
            }
        }
#pragma unroll
        for (int off = 4; off < 64; off <<= 1)
#pragma unroll
            for (int k = 0; k < 8; ++k) acc[k] += __shfl_down(acc[k], off);

        if (slot == 0) {
            float4 o0 = make_float4(acc[0] * dv, acc[1] * dv, acc[2] * dv, acc[3] * dv);
            float4 o1 = make_float4(acc[4] * dv, acc[5] * dv, acc[6] * dv, acc[7] * dv);
            *(float4*)(B + (size_t)n * NF + h * 32 + quad * 8)     = o0;
            *(float4*)(B + (size_t)n * NF + h * 32 + quad * 8 + 4) = o1;
        }
    }
}

// ---------------- fused pool + head: one block per graph -------------------
__device__ __forceinline__ int lower_bound_i(const int* __restrict__ a, int n, int key) {
    int lo = 0, hi = n;
    while (lo < hi) {
        int mid = (lo + hi) >> 1;
        if (a[mid] < key) lo = mid + 1; else hi = mid;
    }
    return lo;
}

__global__ __launch_bounds__(512) void k_pool_final(const float* __restrict__ B,
                                                    const int* __restrict__ batch,
                                                    const float* __restrict__ b2,
                                                    const float* __restrict__ Wfc,
                                                    const float* __restrict__ bfc,
                                                    float* __restrict__ out) {
    int g = blockIdx.x;
    __shared__ int s_lo, s_hi;
    int t = threadIdx.x;
    if (t == 0) {
        s_lo = lower_bound_i(batch, N_NODES, g);
        s_hi = lower_bound_i(batch, N_NODES, g + 1);
    }
    __syncthreads();
    int lo = s_lo, hi = s_hi;
    int ln = t >> 6, lane = t & 63;
    float bias = b2[lane];
    float acc = 0.0f;
    for (int n = lo + ln; n < hi; n += 8) {
        float v = B[(size_t)n * NF + lane] + bias;
        acc += v > 0.0f ? v : 0.0f;
    }
    __shared__ float red[8][64];
    red[ln][lane] = acc;
    __syncthreads();
    if (ln == 0) {
        float tot = 0.0f;
#pragma unroll
        for (int w = 0; w < 8; ++w) tot += red[w][lane];
        int cnt = hi - lo;
        float c = cnt > 0 ? (float)cnt : 1.0f;
        float v = (tot / c) * Wfc[lane];
#pragma unroll
        for (int off = 32; off > 0; off >>= 1) v += __shfl_down(v, off);
        if (lane == 0) out[g] = 1.0f / (1.0f + expf(-(v + bfc[0])));
    }
}

extern "C" void kernel_launch(void* const* d_in, const int* in_sizes, int n_in,
                              void* d_out, int out_size, void* d_ws, size_t ws_size,
                              hipStream_t stream) {
    const float* x    = (const float*)d_in[0];
    const int*   ei   = (const int*)d_in[1];
    const int*   batch= (const int*)d_in[2];
    const float* W1   = (const float*)d_in[3];
    const float* b1   = (const float*)d_in[4];
    const float* W2   = (const float*)d_in[5];
    const float* b2   = (const float*)d_in[6];
    const float* Wfc  = (const float*)d_in[7];
    const float* bfc  = (const float*)d_in[8];
    float* out = (float*)d_out;

    const int* src = ei;
    const int* dst = ei + N_EDGES;

    // workspace layout
    float* B         = (float*)d_ws;                        // N*64 fp32
    int*   Aa        = (int*)(B + (size_t)N_NODES * NF);    // N*8 ints (fp8 half-rows)
    int*   Ab        = Aa + (size_t)N_NODES * 8;            // N*8
    float* dinv      = (float*)(Ab + (size_t)N_NODES * 8);  // N
    int*   rowptr    = (int*)(dinv + N_NODES);              // N+1
    int*   bucketCur = rowptr + N_NODES + 1;                // NB
    int*   bucketPtr = bucketCur + NB;                      // NB+1
    int*   col       = bucketPtr + NB + 1;                  // E
    int*   scratch   = col + N_EDGES;                       // NB*BCAP (~8.1 MB)

    const int BLK = 256;
    int g_nwave = (N_NODES + 3) / 4;                        // 25000
    int g_bsc   = (N_EDGES / 8 + 1023) / 1024;              // 196

    // ---- CSR build (counting sort by 128-node buckets) ----
    k_zerocur<<<(NB + BLK - 1) / BLK, BLK, 0, stream>>>(bucketCur);
    k_bscatter<<<g_bsc, 1024, 0, stream>>>(src, dst, bucketCur, scratch);
    k_bscan<<<1, 1024, 0, stream>>>(bucketCur, bucketPtr, rowptr);
    k_bfinal<<<NB, BLK, 0, stream>>>(bucketCur, bucketPtr, scratch, rowptr, dinv, col);

    // ---- layer 1 ----  A = fp8(dinv*(x@W1)) ; B = pull(A)
    k_gemm<<<NBLKS, BLK, 0, stream>>>(x, W1, nullptr, dinv, Aa, Ab);
    k_pull<<<g_nwave, BLK, 0, stream>>>(rowptr, col, dinv, Aa, Ab, B);

    // ---- layer 2 ----  A = fp8(dinv*(relu(B+b1)@W2)) ; B = pull(A)
    k_gemm<<<NBLKS, BLK, 0, stream>>>(B, W2, b1, dinv, Aa, Ab);
    k_pull<<<g_nwave, BLK, 0, stream>>>(rowptr, col, dinv, Aa, Ab, B);

    // ---- fused pool + bias2 + relu + fc + sigmoid ----
    k_pool_final<<<N_GRAPHS, 512, 0, stream>>>(B, batch, b2, Wfc, bfc, out);
}

// Round 13
// 311.963 us; speedup vs baseline: 1.3429x; 1.0011x over previous
//
#include <hip/hip_runtime.h>
#include <math.h>

#define N_NODES  100000
#define N_EDGES  1600000
#define NF       64
#define N_GRAPHS 256

#define BSH   7                                   // 128 nodes per bucket
#define NB    ((N_NODES + 127) / 128)             // 782 buckets
#define BCAP  2600                                // per-bucket scratch capacity
#define NBLKS ((N_NODES + 63) / 64)               // 1563 node-tile blocks

typedef float f32x2 __attribute__((ext_vector_type(2)));

// ---------------- zero bucket allocator ------------------------------------
__global__ void k_zerocur(int* __restrict__ bucketCur) {
    int i = blockIdx.x * blockDim.x + threadIdx.x;
    if (i < NB) bucketCur[i] = 0;
}

// ---------------- bucket scatter: LDS-aggregated, 1 atomic/(block,bucket) --
__global__ __launch_bounds__(1024) void k_bscatter(const int* __restrict__ src,
                                                   const int* __restrict__ dst,
                                                   int* __restrict__ bucketCur,
                                                   int* __restrict__ scratch) {
    __shared__ int hist[NB];
    __shared__ int bbase[NB];
    int t = threadIdx.x;
    for (int i = t; i < NB; i += 1024) hist[i] = 0;
    __syncthreads();
    int e0 = (blockIdx.x * 1024 + t) * 8;
    int d[8], s[8], r[8];
    bool act = (e0 + 7) < N_EDGES;          // E % 8 == 0
    if (act) {
        *(int4*)&d[0] = *(const int4*)(dst + e0);
        *(int4*)&d[4] = *(const int4*)(dst + e0 + 4);
        *(int4*)&s[0] = *(const int4*)(src + e0);
        *(int4*)&s[4] = *(const int4*)(src + e0 + 4);
#pragma unroll
        for (int k = 0; k < 8; ++k) r[k] = atomicAdd(&hist[d[k] >> BSH], 1);
    }
    __syncthreads();
    for (int i = t; i < NB; i += 1024)
        if (hist[i]) bbase[i] = atomicAdd(&bucketCur[i], hist[i]);
    __syncthreads();
    if (act) {
#pragma unroll
        for (int k = 0; k < 8; ++k) {
            int b = d[k] >> BSH;
            int pos = bbase[b] + r[k];
            if (pos < BCAP)
                scratch[b * BCAP + pos] = ((d[k] & 127) << 17) | s[k];
        }
    }
}

// ---------------- scan bucket counts -> bucketPtr --------------------------
__global__ __launch_bounds__(1024) void k_bscan(const int* __restrict__ bucketCur,
                                                int* __restrict__ bucketPtr,
                                                int* __restrict__ rowptr) {
    int t = threadIdx.x;
    __shared__ int ps[1024];
    int v = (t < NB) ? min(bucketCur[t], BCAP) : 0;
    ps[t] = v;
    __syncthreads();
#pragma unroll
    for (int off = 1; off < 1024; off <<= 1) {
        int u = (t >= off) ? ps[t - off] : 0;
        __syncthreads();
        ps[t] += u;
        __syncthreads();
    }
    if (t < NB) bucketPtr[t] = ps[t] - v;        // exclusive
    if (t == NB - 1) {
        bucketPtr[NB] = ps[t];
        rowptr[N_NODES] = ps[t];                 // == N_EDGES
    }
}

// ---------------- per-bucket CSR finalize: rowptr, dinv, col ---------------
__global__ __launch_bounds__(256) void k_bfinal(const int* __restrict__ bucketCur,
                                                const int* __restrict__ bucketPtr,
                                                const int* __restrict__ scratch,
                                                int* __restrict__ rowptr,
                                                float* __restrict__ dinv,
                                                int* __restrict__ col) {
    int b = blockIdx.x;
    int cnt  = min(bucketCur[b], BCAP);
    int base = bucketPtr[b];
    int node0 = b << BSH;
    __shared__ int hist[128];
    __shared__ int escan[128];
    __shared__ int ps[128];
    __shared__ int rnk[BCAP];
    int t = threadIdx.x;
    if (t < 128) hist[t] = 0;
    __syncthreads();
    const int* sp = scratch + b * BCAP;
    for (int j = t; j < cnt; j += 256)
        rnk[j] = atomicAdd(&hist[sp[j] >> 17], 1);
    __syncthreads();
    int hv = (t < 128) ? hist[t] : 0;
    if (t < 128) ps[t] = hv;
    __syncthreads();
#pragma unroll
    for (int off = 1; off < 128; off <<= 1) {
        int u = 0;
        if (t < 128 && t >= off) u = ps[t - off];
        __syncthreads();
        if (t < 128) ps[t] += u;
        __syncthreads();
    }
    if (t < 128) {
        int excl = ps[t] - hv;
        escan[t] = excl;
        int node = node0 + t;
        if (node < N_NODES) {
            rowptr[node] = base + excl;
            dinv[node] = rsqrtf((float)(hv + 1));   // self-loop adds 1
        }
    }
    __syncthreads();
    for (int j = t; j < cnt; j += 256) {
        int pk = sp[j];
        col[base + escan[pk >> 17] + rnk[j]] = pk & 0x1FFFF;
    }
}

// ---------------- A' = dinv * (act(X [+bias,relu]) @ W), stored fp8 --------
// Block tile: 64 nodes x 64 cols; thread tile 4x4. Row = 16 ints = 64 B.
__global__ __launch_bounds__(256) void k_gemm(const float* __restrict__ X,
                                              const float* __restrict__ W,
                                              const float* __restrict__ bias,
                                              const float* __restrict__ dinv,
                                              int* __restrict__ Ah8) {
    __shared__ float Ws[64][64];       // [k][col]
    __shared__ float Xs[64][68];       // [k][node], padded
    int t  = threadIdx.x;
    int n0 = blockIdx.x * 64;

    for (int i = t; i < 64 * 64; i += 256) Ws[i >> 6][i & 63] = W[i];

#pragma unroll
    for (int p = 0; p < 4; ++p) {
        int flat = p * 256 + t;                  // 0..1023
        int nl = flat >> 4;                      // local node 0..63
        int kg = flat & 15;                      // k-group (4 floats)
        int node = n0 + nl;
        float4 v = make_float4(0.f, 0.f, 0.f, 0.f);
        if (node < N_NODES) {
            v = *(const float4*)(X + (size_t)node * NF + kg * 4);
            if (bias) {
                v.x += bias[kg * 4 + 0]; v.x = v.x > 0.f ? v.x : 0.f;
                v.y += bias[kg * 4 + 1]; v.y = v.y > 0.f ? v.y : 0.f;
                v.z += bias[kg * 4 + 2]; v.z = v.z > 0.f ? v.z : 0.f;
                v.w += bias[kg * 4 + 3]; v.w = v.w > 0.f ? v.w : 0.f;
            }
        }
        Xs[kg * 4 + 0][nl] = v.x;
        Xs[kg * 4 + 1][nl] = v.y;
        Xs[kg * 4 + 2][nl] = v.z;
        Xs[kg * 4 + 3][nl] = v.w;
    }
    __syncthreads();

    int tx = t & 15;          // col group: cols 4*tx..+3
    int ty = t >> 4;          // node group: nodes 4*ty..+3
    float acc[4][4];
#pragma unroll
    for (int i = 0; i < 4; ++i)
#pragma unroll
        for (int j = 0; j < 4; ++j) acc[i][j] = 0.f;

#pragma unroll 8
    for (int k = 0; k < 64; ++k) {
        float4 wv = *(const float4*)&Ws[k][tx * 4];
        float4 xv = *(const float4*)&Xs[k][ty * 4];
        acc[0][0] += xv.x * wv.x; acc[0][1] += xv.x * wv.y;
        acc[0][2] += xv.x * wv.z; acc[0][3] += xv.x * wv.w;
        acc[1][0] += xv.y * wv.x; acc[1][1] += xv.y * wv.y;
        acc[1][2] += xv.y * wv.z; acc[1][3] += xv.y * wv.w;
        acc[2][0] += xv.z * wv.x; acc[2][1] += xv.z * wv.y;
        acc[2][2] += xv.z * wv.z; acc[2][3] += xv.z * wv.w;
        acc[3][0] += xv.w * wv.x; acc[3][1] += xv.w * wv.y;
        acc[3][2] += xv.w * wv.z; acc[3][3] += xv.w * wv.w;
    }

#pragma unroll
    for (int i = 0; i < 4; ++i) {
        int node = n0 + ty * 4 + i;
        if (node < N_NODES) {
            float dv = dinv[node];
            int pk = 0;
            pk = __builtin_amdgcn_cvt_pk_fp8_f32(acc[i][0] * dv, acc[i][1] * dv, pk, false);
            pk = __builtin_amdgcn_cvt_pk_fp8_f32(acc[i][2] * dv, acc[i][3] * dv, pk, true);
            Ah8[(size_t)node * 16 + tx] = pk;
        }
    }
}

// ---------------- pull aggregation: 4 lanes/row, int4 loads ----------------
// Row = 64 B. quad = lane&3 picks a 16 B chunk (16 features), slot = lane>>2
// picks the edge: 16 edge slots in flight, 6.4M vmem requests per pull.
__global__ __launch_bounds__(256) void k_pull(const int* __restrict__ rowptr,
                                              const int* __restrict__ col,
                                              const float* __restrict__ dinv,
                                              const int* __restrict__ Ah8,
                                              float* __restrict__ B) {
    int n    = (blockIdx.x * blockDim.x + threadIdx.x) >> 6;
    int lane = threadIdx.x & 63;
    if (n >= N_NODES) return;
    int slot = lane >> 2;       // 16 edge slots
    int quad = lane & 3;        // 16B feature chunk
    int beg = rowptr[n];
    int cnt = rowptr[n + 1] - beg + 1;      // + self
    float dv = dinv[n];

    float acc[16];
#pragma unroll
    for (int k = 0; k < 16; ++k) acc[k] = 0.f;

    for (int base = slot; base < cnt; base += 64) {
        int cidx[4];
#pragma unroll
        for (int p = 0; p < 4; ++p) {
            int idx = base + p * 16;
            cidx[p] = (idx < cnt)
                      ? ((idx == 0) ? n : __builtin_nontemporal_load(col + beg + idx - 1))
                      : -1;
        }
#pragma unroll
        for (int p = 0; p < 4; ++p) {
            int s = cidx[p];
            if (s >= 0) {
                int4 raw = *(const int4*)(Ah8 + (size_t)s * 16 + quad * 4);
                f32x2 f0 = __builtin_amdgcn_cvt_pk_f32_fp8(raw.x, false);
                f32x2 f1 = __builtin_amdgcn_cvt_pk_f32_fp8(raw.x, true);
                f32x2 f2 = __builtin_amdgcn_cvt_pk_f32_fp8(raw.y, false);
                f32x2 f3 = __builtin_amdgcn_cvt_pk_f32_fp8(raw.y, true);
                f32x2 f4 = __builtin_amdgcn_cvt_pk_f32_fp8(raw.z, false);
                f32x2 f5 = __builtin_amdgcn_cvt_pk_f32_fp8(raw.z, true);
                f32x2 f6 = __builtin_amdgcn_cvt_pk_f32_fp8(raw.w, false);
                f32x2 f7 = __builtin_amdgcn_cvt_pk_f32_fp8(raw.w, true);
                acc[0]  += f0.x; acc[1]  += f0.y; acc[2]  += f1.x; acc[3]  += f1.y;
                acc[4]  += f2.x; acc[5]  += f2.y; acc[6]  += f3.x; acc[7]  += f3.y;
                acc[8]  += f4.x; acc[9]  += f4.y; acc[10] += f5.x; acc[11] += f5.y;
                acc[12] += f6.x; acc[13] += f6.y; acc[14] += f7.x; acc[15] += f7.y;
            }
        }
    }
#pragma unroll
    for (int off = 4; off < 64; off <<= 1)
#pragma unroll
        for (int k = 0; k < 16; ++k) acc[k] += __shfl_down(acc[k], off);

    if (slot == 0) {
        float* bp = B + (size_t)n * NF + quad * 16;
#pragma unroll
        for (int q = 0; q < 4; ++q) {
            float4 o = make_float4(acc[q*4+0] * dv, acc[q*4+1] * dv,
                                   acc[q*4+2] * dv, acc[q*4+3] * dv);
            *(float4*)(bp + q * 4) = o;
        }
    }
}

// ---------------- fused pool + head: one block per graph -------------------
__device__ __forceinline__ int lower_bound_i(const int* __restrict__ a, int n, int key) {
    int lo = 0, hi = n;
    while (lo < hi) {
        int mid = (lo + hi) >> 1;
        if (a[mid] < key) lo = mid + 1; else hi = mid;
    }
    return lo;
}

__global__ __launch_bounds__(512) void k_pool_final(const float* __restrict__ B,
                                                    const int* __restrict__ batch,
                                                    const float* __restrict__ b2,
                                                    const float* __restrict__ Wfc,
                                                    const float* __restrict__ bfc,
                                                    float* __restrict__ out) {
    int g = blockIdx.x;
    __shared__ int s_lo, s_hi;
    int t = threadIdx.x;
    if (t == 0) {
        s_lo = lower_bound_i(batch, N_NODES, g);
        s_hi = lower_bound_i(batch, N_NODES, g + 1);
    }
    __syncthreads();
    int lo = s_lo, hi = s_hi;
    int ln = t >> 6, lane = t & 63;
    float bias = b2[lane];
    float acc = 0.0f;
    for (int n = lo + ln; n < hi; n += 8) {
        float v = B[(size_t)n * NF + lane] + bias;
        acc += v > 0.0f ? v : 0.0f;
    }
    __shared__ float red[8][64];
    red[ln][lane] = acc;
    __syncthreads();
    if (ln == 0) {
        float tot = 0.0f;
#pragma unroll
        for (int w = 0; w < 8; ++w) tot += red[w][lane];
        int cnt = hi - lo;
        float c = cnt > 0 ? (float)cnt : 1.0f;
        float v = (tot / c) * Wfc[lane];
#pragma unroll
        for (int off = 32; off > 0; off >>= 1) v += __shfl_down(v, off);
        if (lane == 0) out[g] = 1.0f / (1.0f + expf(-(v + bfc[0])));
    }
}

extern "C" void kernel_launch(void* const* d_in, const int* in_sizes, int n_in,
                              void* d_out, int out_size, void* d_ws, size_t ws_size,
                              hipStream_t stream) {
    const float* x    = (const float*)d_in[0];
    const int*   ei   = (const int*)d_in[1];
    const int*   batch= (const int*)d_in[2];
    const float* W1   = (const float*)d_in[3];
    const float* b1   = (const float*)d_in[4];
    const float* W2   = (const float*)d_in[5];
    const float* b2   = (const float*)d_in[6];
    const float* Wfc  = (const float*)d_in[7];
    const float* bfc  = (const float*)d_in[8];
    float* out = (float*)d_out;

    const int* src = ei;
    const int* dst = ei + N_EDGES;

    // workspace layout
    float* B         = (float*)d_ws;                        // N*64 fp32
    int*   Ah8       = (int*)(B + (size_t)N_NODES * NF);    // N*16 ints (fp8 rows)
    float* dinv      = (float*)(Ah8 + (size_t)N_NODES * 16);// N
    int*   rowptr    = (int*)(dinv + N_NODES);              // N+1
    int*   bucketCur = rowptr + N_NODES + 1;                // NB
    int*   bucketPtr = bucketCur + NB;                      // NB+1
    int*   col       = bucketPtr + NB + 1;                  // E
    int*   scratch   = col + N_EDGES;                       // NB*BCAP (~8.1 MB)

    const int BLK = 256;
    int g_nwave = (N_NODES + 3) / 4;                        // 25000
    int g_bsc   = (N_EDGES / 8 + 1023) / 1024;              // 196

    // ---- CSR build (counting sort by 128-node buckets) ----
    k_zerocur<<<(NB + BLK - 1) / BLK, BLK, 0, stream>>>(bucketCur);
    k_bscatter<<<g_bsc, 1024, 0, stream>>>(src, dst, bucketCur, scratch);
    k_bscan<<<1, 1024, 0, stream>>>(bucketCur, bucketPtr, rowptr);
    k_bfinal<<<NB, BLK, 0, stream>>>(bucketCur, bucketPtr, scratch, rowptr, dinv, col);

    // ---- layer 1 ----  A = fp8(dinv*(x@W1)) ; B = pull(A)
    k_gemm<<<NBLKS, BLK, 0, stream>>>(x, W1, nullptr, dinv, Ah8);
    k_pull<<<g_nwave, BLK, 0, stream>>>(rowptr, col, dinv, Ah8, B);

    // ---- layer 2 ----  A = fp8(dinv*(relu(B+b1)@W2)) ; B = pull(A)
    k_gemm<<<NBLKS, BLK, 0, stream>>>(B, W2, b1, dinv, Ah8);
    k_pull<<<g_nwave, BLK, 0, stream>>>(rowptr, col, dinv, Ah8, B);

    // ---- fused pool + bias2 + relu + fc + sigmoid ----
    k_pool_final<<<N_GRAPHS, 512, 0, stream>>>(B, batch, b2, Wfc, bfc, out);
}

// Round 15
// 267.837 us; speedup vs baseline: 1.5641x; 1.1647x over previous
//
#include <hip/hip_runtime.h>
#include <math.h>

#define N_NODES  100000
#define N_EDGES  1600000
#define NF       64
#define N_GRAPHS 256
#define HALF_N   50000

#define BSH   7                                   // 128 nodes per bucket
#define NB    ((N_NODES + 127) / 128)             // 782 buckets
#define BCAP  2600                                // per-bucket scratch capacity
#define NBLKS ((N_NODES + 63) / 64)               // 1563 node-tile blocks

typedef float f32x2 __attribute__((ext_vector_type(2)));

// ---------------- zero bucket allocator ------------------------------------
__global__ void k_zerocur(int* __restrict__ bucketCur) {
    int i = blockIdx.x * blockDim.x + threadIdx.x;
    if (i < NB) bucketCur[i] = 0;
}

// ---------------- bucket scatter: LDS-aggregated, 1 atomic/(block,bucket) --
__global__ __launch_bounds__(1024) void k_bscatter(const int* __restrict__ src,
                                                   const int* __restrict__ dst,
                                                   int* __restrict__ bucketCur,
                                                   int* __restrict__ scratch) {
    __shared__ int hist[NB];
    __shared__ int bbase[NB];
    int t = threadIdx.x;
    for (int i = t; i < NB; i += 1024) hist[i] = 0;
    __syncthreads();
    int e0 = (blockIdx.x * 1024 + t) * 8;
    int d[8], s[8], r[8];
    bool act = (e0 + 7) < N_EDGES;          // E % 8 == 0
    if (act) {
        *(int4*)&d[0] = *(const int4*)(dst + e0);
        *(int4*)&d[4] = *(const int4*)(dst + e0 + 4);
        *(int4*)&s[0] = *(const int4*)(src + e0);
        *(int4*)&s[4] = *(const int4*)(src + e0 + 4);
#pragma unroll
        for (int k = 0; k < 8; ++k) r[k] = atomicAdd(&hist[d[k] >> BSH], 1);
    }
    __syncthreads();
    for (int i = t; i < NB; i += 1024)
        if (hist[i]) bbase[i] = atomicAdd(&bucketCur[i], hist[i]);
    __syncthreads();
    if (act) {
#pragma unroll
        for (int k = 0; k < 8; ++k) {
            int b = d[k] >> BSH;
            int pos = bbase[b] + r[k];
            if (pos < BCAP)
                scratch[b * BCAP + pos] = ((d[k] & 127) << 17) | s[k];
        }
    }
}

// ---------------- scan bucket counts -> bucketPtr --------------------------
__global__ __launch_bounds__(1024) void k_bscan(const int* __restrict__ bucketCur,
                                                int* __restrict__ bucketPtr,
                                                int* __restrict__ rowptr) {
    int t = threadIdx.x;
    __shared__ int ps[1024];
    int v = (t < NB) ? min(bucketCur[t], BCAP) : 0;
    ps[t] = v;
    __syncthreads();
#pragma unroll
    for (int off = 1; off < 1024; off <<= 1) {
        int u = (t >= off) ? ps[t - off] : 0;
        __syncthreads();
        ps[t] += u;
        __syncthreads();
    }
    if (t < NB) bucketPtr[t] = ps[t] - v;        // exclusive
    if (t == NB - 1) {
        bucketPtr[NB] = ps[t];
        rowptr[N_NODES] = ps[t];                 // == N_EDGES
    }
}

// ---------------- per-bucket CSR finalize: rowptr, midptr, dinv, col -------
// Each row's col entries are partitioned: src < HALF_N first, then >= HALF_N.
// 256 bins: bin = local*2 + (src >= HALF_N).
__global__ __launch_bounds__(256) void k_bfinal(const int* __restrict__ bucketCur,
                                                const int* __restrict__ bucketPtr,
                                                const int* __restrict__ scratch,
                                                int* __restrict__ rowptr,
                                                int* __restrict__ midptr,
                                                float* __restrict__ dinv,
                                                int* __restrict__ col) {
    int b = blockIdx.x;
    int cnt  = min(bucketCur[b], BCAP);
    int base = bucketPtr[b];
    int node0 = b << BSH;
    __shared__ int hist[256];
    __shared__ int escan[256];
    __shared__ int ps[256];
    __shared__ int rnk[BCAP];
    int t = threadIdx.x;
    hist[t] = 0;
    __syncthreads();
    const int* sp = scratch + b * BCAP;
    for (int j = t; j < cnt; j += 256) {
        int pk = sp[j];
        int bin = ((pk >> 17) << 1) | ((pk & 0x1FFFF) >= HALF_N ? 1 : 0);
        rnk[j] = atomicAdd(&hist[bin], 1);
    }
    __syncthreads();
    int hv = hist[t];
    ps[t] = hv;
    __syncthreads();
#pragma unroll
    for (int off = 1; off < 256; off <<= 1) {
        int u = (t >= off) ? ps[t - off] : 0;
        __syncthreads();
        ps[t] += u;
        __syncthreads();
    }
    escan[t] = ps[t] - hv;          // exclusive over bins
    __syncthreads();
    if (t < 128) {
        int node = node0 + t;
        if (node < N_NODES) {
            rowptr[node] = base + escan[t * 2];
            midptr[node] = base + escan[t * 2 + 1];
            int deg = hist[t * 2] + hist[t * 2 + 1];
            dinv[node] = rsqrtf((float)(deg + 1));   // self-loop adds 1
        }
    }
    __syncthreads();
    for (int j = t; j < cnt; j += 256) {
        int pk = sp[j];
        int s = pk & 0x1FFFF;
        int bin = ((pk >> 17) << 1) | (s >= HALF_N ? 1 : 0);
        col[base + escan[bin] + rnk[j]] = s;
    }
}

// ---------------- A' = dinv * (act(X [+bias,relu]) @ W), stored fp8 --------
// Block tile: 64 nodes x 64 cols; thread tile 4x4. Row = 16 ints = 64 B.
__global__ __launch_bounds__(256) void k_gemm(const float* __restrict__ X,
                                              const float* __restrict__ W,
                                              const float* __restrict__ bias,
                                              const float* __restrict__ dinv,
                                              int* __restrict__ Ah8) {
    __shared__ float Ws[64][64];       // [k][col]
    __shared__ float Xs[64][68];       // [k][node], padded
    int t  = threadIdx.x;
    int n0 = blockIdx.x * 64;

    for (int i = t; i < 64 * 64; i += 256) Ws[i >> 6][i & 63] = W[i];

#pragma unroll
    for (int p = 0; p < 4; ++p) {
        int flat = p * 256 + t;                  // 0..1023
        int nl = flat >> 4;                      // local node 0..63
        int kg = flat & 15;                      // k-group (4 floats)
        int node = n0 + nl;
        float4 v = make_float4(0.f, 0.f, 0.f, 0.f);
        if (node < N_NODES) {
            v = *(const float4*)(X + (size_t)node * NF + kg * 4);
            if (bias) {
                v.x += bias[kg * 4 + 0]; v.x = v.x > 0.f ? v.x : 0.f;
                v.y += bias[kg * 4 + 1]; v.y = v.y > 0.f ? v.y : 0.f;
                v.z += bias[kg * 4 + 2]; v.z = v.z > 0.f ? v.z : 0.f;
                v.w += bias[kg * 4 + 3]; v.w = v.w > 0.f ? v.w : 0.f;
            }
        }
        Xs[kg * 4 + 0][nl] = v.x;
        Xs[kg * 4 + 1][nl] = v.y;
        Xs[kg * 4 + 2][nl] = v.z;
        Xs[kg * 4 + 3][nl] = v.w;
    }
    __syncthreads();

    int tx = t & 15;          // col group: cols 4*tx..+3
    int ty = t >> 4;          // node group: nodes 4*ty..+3
    float acc[4][4];
#pragma unroll
    for (int i = 0; i < 4; ++i)
#pragma unroll
        for (int j = 0; j < 4; ++j) acc[i][j] = 0.f;

#pragma unroll 8
    for (int k = 0; k < 64; ++k) {
        float4 wv = *(const float4*)&Ws[k][tx * 4];
        float4 xv = *(const float4*)&Xs[k][ty * 4];
        acc[0][0] += xv.x * wv.x; acc[0][1] += xv.x * wv.y;
        acc[0][2] += xv.x * wv.z; acc[0][3] += xv.x * wv.w;
        acc[1][0] += xv.y * wv.x; acc[1][1] += xv.y * wv.y;
        acc[1][2] += xv.y * wv.z; acc[1][3] += xv.y * wv.w;
        acc[2][0] += xv.z * wv.x; acc[2][1] += xv.z * wv.y;
        acc[2][2] += xv.z * wv.z; acc[2][3] += xv.z * wv.w;
        acc[3][0] += xv.w * wv.x; acc[3][1] += xv.w * wv.y;
        acc[3][2] += xv.w * wv.z; acc[3][3] += xv.w * wv.w;
    }

#pragma unroll
    for (int i = 0; i < 4; ++i) {
        int node = n0 + ty * 4 + i;
        if (node < N_NODES) {
            float dv = dinv[node];
            int pk = 0;
            pk = __builtin_amdgcn_cvt_pk_fp8_f32(acc[i][0] * dv, acc[i][1] * dv, pk, false);
            pk = __builtin_amdgcn_cvt_pk_fp8_f32(acc[i][2] * dv, acc[i][3] * dv, pk, true);
            Ah8[(size_t)node * 16 + tx] = pk;
        }
    }
}

// ---------------- pull aggregation: R10 loop, two L2-resident phases -------
// Row = 64 B. slot = lane>>3 picks edge (8 slots), oct = lane&7 picks 8 B.
// Phase 0 gathers rows < HALF_N (first 3.2 MB), phase 1 the rest.
__global__ __launch_bounds__(256) void k_pull(const int* __restrict__ rowptr,
                                              const int* __restrict__ midptr,
                                              const int* __restrict__ col,
                                              const float* __restrict__ dinv,
                                              const int* __restrict__ Ah8,
                                              float* __restrict__ B) {
    int n    = (blockIdx.x * blockDim.x + threadIdx.x) >> 6;
    int lane = threadIdx.x & 63;
    if (n >= N_NODES) return;
    int slot = lane >> 3;
    int oct  = lane & 7;
    int beg = rowptr[n], mid = midptr[n], end = rowptr[n + 1];
    float dv = dinv[n];

    float acc0 = 0.f, acc1 = 0.f, acc2 = 0.f, acc3 = 0.f;
    float acc4 = 0.f, acc5 = 0.f, acc6 = 0.f, acc7 = 0.f;

#pragma unroll
    for (int ph = 0; ph < 2; ++ph) {
        int lo = ph ? mid : beg;
        int hi = ph ? end : mid;
        int selfin = (ph == (n >= HALF_N ? 1 : 0)) ? 1 : 0;
        int cnt = hi - lo + selfin;

        for (int base = slot; base < cnt; base += 32) {
            int cidx[4];
#pragma unroll
            for (int p = 0; p < 4; ++p) {
                int idx = base + p * 8;
                cidx[p] = (idx < cnt)
                          ? ((selfin && idx == 0) ? n : col[lo + idx - selfin])
                          : -1;
            }
#pragma unroll
            for (int p = 0; p < 4; ++p) {
                int s = cidx[p];
                if (s >= 0) {
                    int2 raw = *(const int2*)(Ah8 + (size_t)s * 16 + oct * 2);
                    f32x2 f0 = __builtin_amdgcn_cvt_pk_f32_fp8(raw.x, false);
                    f32x2 f1 = __builtin_amdgcn_cvt_pk_f32_fp8(raw.x, true);
                    f32x2 f2 = __builtin_amdgcn_cvt_pk_f32_fp8(raw.y, false);
                    f32x2 f3 = __builtin_amdgcn_cvt_pk_f32_fp8(raw.y, true);
                    acc0 += f0.x; acc1 += f0.y;
                    acc2 += f1.x; acc3 += f1.y;
                    acc4 += f2.x; acc5 += f2.y;
                    acc6 += f3.x; acc7 += f3.y;
                }
            }
        }
    }
#pragma unroll
    for (int off = 8; off < 64; off <<= 1) {
        acc0 += __shfl_down(acc0, off);
        acc1 += __shfl_down(acc1, off);
        acc2 += __shfl_down(acc2, off);
        acc3 += __shfl_down(acc3, off);
        acc4 += __shfl_down(acc4, off);
        acc5 += __shfl_down(acc5, off);
        acc6 += __shfl_down(acc6, off);
        acc7 += __shfl_down(acc7, off);
    }
    if (slot == 0) {
        float4 o0 = make_float4(acc0 * dv, acc1 * dv, acc2 * dv, acc3 * dv);
        float4 o1 = make_float4(acc4 * dv, acc5 * dv, acc6 * dv, acc7 * dv);
        *(float4*)(B + (size_t)n * NF + oct * 8)     = o0;
        *(float4*)(B + (size_t)n * NF + oct * 8 + 4) = o1;
    }
}

// ---------------- fused pool + head: one block per graph -------------------
__device__ __forceinline__ int lower_bound_i(const int* __restrict__ a, int n, int key) {
    int lo = 0, hi = n;
    while (lo < hi) {
        int mid = (lo + hi) >> 1;
        if (a[mid] < key) lo = mid + 1; else hi = mid;
    }
    return lo;
}

__global__ __launch_bounds__(512) void k_pool_final(const float* __restrict__ B,
                                                    const int* __restrict__ batch,
                                                    const float* __restrict__ b2,
                                                    const float* __restrict__ Wfc,
                                                    const float* __restrict__ bfc,
                                                    float* __restrict__ out) {
    int g = blockIdx.x;
    __shared__ int s_lo, s_hi;
    int t = threadIdx.x;
    if (t == 0) {
        s_lo = lower_bound_i(batch, N_NODES, g);
        s_hi = lower_bound_i(batch, N_NODES, g + 1);
    }
    __syncthreads();
    int lo = s_lo, hi = s_hi;
    int ln = t >> 6, lane = t & 63;
    float bias = b2[lane];
    float acc = 0.0f;
    for (int n = lo + ln; n < hi; n += 8) {
        float v = B[(size_t)n * NF + lane] + bias;
        acc += v > 0.0f ? v : 0.0f;
    }
    __shared__ float red[8][64];
    red[ln][lane] = acc;
    __syncthreads();
    if (ln == 0) {
        float tot = 0.0f;
#pragma unroll
        for (int w = 0; w < 8; ++w) tot += red[w][lane];
        int cnt = hi - lo;
        float c = cnt > 0 ? (float)cnt : 1.0f;
        float v = (tot / c) * Wfc[lane];
#pragma unroll
        for (int off = 32; off > 0; off >>= 1) v += __shfl_down(v, off);
        if (lane == 0) out[g] = 1.0f / (1.0f + expf(-(v + bfc[0])));
    }
}

extern "C" void kernel_launch(void* const* d_in, const int* in_sizes, int n_in,
                              void* d_out, int out_size, void* d_ws, size_t ws_size,
                              hipStream_t stream) {
    const float* x    = (const float*)d_in[0];
    const int*   ei   = (const int*)d_in[1];
    const int*   batch= (const int*)d_in[2];
    const float* W1   = (const float*)d_in[3];
    const float* b1   = (const float*)d_in[4];
    const float* W2   = (const float*)d_in[5];
    const float* b2   = (const float*)d_in[6];
    const float* Wfc  = (const float*)d_in[7];
    const float* bfc  = (const float*)d_in[8];
    float* out = (float*)d_out;

    const int* src = ei;
    const int* dst = ei + N_EDGES;

    // workspace layout
    float* B         = (float*)d_ws;                        // N*64 fp32
    int*   Ah8       = (int*)(B + (size_t)N_NODES * NF);    // N*16 ints (fp8 rows)
    float* dinv      = (float*)(Ah8 + (size_t)N_NODES * 16);// N
    int*   rowptr    = (int*)(dinv + N_NODES);              // N+1
    int*   midptr    = rowptr + N_NODES + 1;                // N
    int*   bucketCur = midptr + N_NODES;                    // NB
    int*   bucketPtr = bucketCur + NB;                      // NB+1
    int*   col       = bucketPtr + NB + 1;                  // E
    int*   scratch   = col + N_EDGES;                       // NB*BCAP (~8.1 MB)

    const int BLK = 256;
    int g_nwave = (N_NODES + 3) / 4;                        // 25000
    int g_bsc   = (N_EDGES / 8 + 1023) / 1024;              // 196

    // ---- CSR build (counting sort by 128-node buckets) ----
    k_zerocur<<<(NB + BLK - 1) / BLK, BLK, 0, stream>>>(bucketCur);
    k_bscatter<<<g_bsc, 1024, 0, stream>>>(src, dst, bucketCur, scratch);
    k_bscan<<<1, 1024, 0, stream>>>(bucketCur, bucketPtr, rowptr);
    k_bfinal<<<NB, BLK, 0, stream>>>(bucketCur, bucketPtr, scratch, rowptr, midptr, dinv, col);

    // ---- layer 1 ----  A = fp8(dinv*(x@W1)) ; B = pull(A)
    k_gemm<<<NBLKS, BLK, 0, stream>>>(x, W1, nullptr, dinv, Ah8);
    k_pull<<<g_nwave, BLK, 0, stream>>>(rowptr, midptr, col, dinv, Ah8, B);

    // ---- layer 2 ----  A = fp8(dinv*(relu(B+b1)@W2)) ; B = pull(A)
    k_gemm<<<NBLKS, BLK, 0, stream>>>(B, W2, b1, dinv, Ah8);
    k_pull<<<g_nwave, BLK, 0, stream>>>(rowptr, midptr, col, dinv, Ah8, B);

    // ---- fused pool + bias2 + relu + fc + sigmoid ----
    k_pool_final<<<N_GRAPHS, 512, 0, stream>>>(B, batch, b2, Wfc, bfc, out);
}